// Round 3
// baseline (2306.062 us; speedup 1.0000x reference)
//
#include <hip/hip_runtime.h>
#include <hip/hip_bf16.h>

#define NNODES 100000
#define NEDGES 1600000
#define NGRAPH 512
#define DIM    64
#define NLAYER 3

#define NB   1000   // buckets
#define BN   100    // nodes per bucket (NB*BN == NNODES exactly)
#define CAP  2048   // max edges per bucket (mean 1600, sigma 40 -> +11 sigma)
#define SC_BLOCKS 200
#define EPB  8000   // edges per scatter block (SC_BLOCKS*EPB == NEDGES)

__device__ __forceinline__ float b2f(__hip_bfloat16 v) { return __bfloat162float(v); }

// ---------------- bucket build ----------------

__global__ void zero_gcur_kernel(int* __restrict__ gcur) {
    int i = threadIdx.x;
    if (i < NB) gcur[i] = 0;
}

// Edges -> 1000 coarse buckets by dst/100. Per-block LDS histogram, one global
// atomic per (block,bin) to reserve a contiguous region, then ranked scatter of
// packed records {src | dst_local<<20, e_bits}.
__global__ __launch_bounds__(256) void bucket_scatter_kernel(
    const int* __restrict__ ei, const float* __restrict__ ea,
    int* __restrict__ gcur, int2* __restrict__ perm) {
    __shared__ int cnt_l[NB];
    __shared__ int cur_l[NB];
    int tid = threadIdx.x;
    int e0 = blockIdx.x * EPB;
    for (int i = tid; i < NB; i += 256) cnt_l[i] = 0;
    __syncthreads();
    for (int i = tid; i < EPB; i += 256) {
        int d = ei[NEDGES + e0 + i];
        atomicAdd(&cnt_l[d / BN], 1);
    }
    __syncthreads();
    for (int i = tid; i < NB; i += 256) {
        int c = cnt_l[i];
        cur_l[i] = (c > 0) ? atomicAdd(&gcur[i], c) : 0;
    }
    __syncthreads();
    for (int i = tid; i < EPB; i += 256) {
        int e = e0 + i;
        int s = ei[e];
        int d = ei[NEDGES + e];
        float w = ea[e];
        int bin = d / BN;
        int dloc = d - bin * BN;
        int r = atomicAdd(&cur_l[bin], 1);
        if (r < CAP)
            perm[(size_t)bin * CAP + r] = make_int2(s | (dloc << 20), __float_as_int(w));
    }
}

// wdeg[node] = sum of incoming edge weights (from bucketed records, LDS atomics)
__global__ __launch_bounds__(256) void wdeg_kernel(const int2* __restrict__ perm,
                                                   const int* __restrict__ gcur,
                                                   float* __restrict__ wdeg) {
    __shared__ float ws[BN];
    int b = blockIdx.x, tid = threadIdx.x;
    if (tid < BN) ws[tid] = 0.f;
    __syncthreads();
    int n = min(gcur[b], CAP);
    const int2* ep = perm + (size_t)b * CAP;
    for (int i = tid; i < n; i += 256) {
        int2 rec = ep[i];
        atomicAdd(&ws[rec.x >> 20], __int_as_float(rec.y));
    }
    __syncthreads();
    if (tid < BN) wdeg[b * BN + tid] = ws[tid];
}

// ---------------- dense ----------------

__global__ void embed_kernel(const float* __restrict__ x,
                             const float* __restrict__ W,
                             const float* __restrict__ b,
                             float* __restrict__ h) {
    int gid = blockIdx.x * 256 + threadIdx.x;
    if (gid >= NNODES * 64) return;
    int n = gid >> 6, cch = gid & 63;
    float s = b[cch];
    #pragma unroll
    for (int k = 0; k < 4; ++k) s = fmaf(x[n * 4 + k], W[k * 64 + cch], s);
    h[gid] = s;
}

// a_bf = bf16(h@W1 + b1) ; h <- h@W3 + b3 - wdeg*(h@W2)   (in-place c; safe:
// each 16-row group is read fully before its stores, only by its own wave)
__global__ __launch_bounds__(256) void gemm3_kernel(
    float* __restrict__ h, const float* __restrict__ wdeg,
    const float* __restrict__ W1, const float* __restrict__ b1,
    const float* __restrict__ W2,
    const float* __restrict__ W3, const float* __restrict__ b3,
    __hip_bfloat16* __restrict__ a) {
    __shared__ float w1s[4096], w2s[4096], w3s[4096];
    __shared__ float b1s[64], b3s[64];
    int tid = threadIdx.x;
    for (int i = tid; i < 4096; i += 256) {
        w1s[i] = W1[i]; w2s[i] = W2[i]; w3s[i] = W3[i];
    }
    if (tid < 64) { b1s[tid] = b1[tid]; b3s[tid] = b3[tid]; }
    __syncthreads();
    const int cch = tid & 63;
    const int sub = tid >> 6;
    int n0 = blockIdx.x * 64 + sub * 16;
    if (n0 >= NNODES) return;
    int nv = min(16, NNODES - n0);
    float acc1[16] = {0.f}, acc2[16] = {0.f}, acc3[16] = {0.f};
    float* hrow = h + (size_t)n0 * 64;
    for (int k = 0; k < 64; ++k) {
        float w1v = w1s[k * 64 + cch];
        float w2v = w2s[k * 64 + cch];
        float w3v = w3s[k * 64 + cch];
        #pragma unroll
        for (int j = 0; j < 16; ++j) {
            if (j < nv) {
                float hv = hrow[j * 64 + k];
                acc1[j] = fmaf(hv, w1v, acc1[j]);
                acc2[j] = fmaf(hv, w2v, acc2[j]);
                acc3[j] = fmaf(hv, w3v, acc3[j]);
            }
        }
    }
    #pragma unroll
    for (int j = 0; j < 16; ++j) {
        if (j < nv) {
            int n = n0 + j;
            a[(size_t)n * 64 + cch] = __float2bfloat16(acc1[j] + b1s[cch]);
            hrow[(size_t)j * 64 + cch] = acc3[j] + b3s[cch] - wdeg[n] * acc2[j];
        }
    }
}

// h = relu(h + sum_{edges into node} e * a[src]) per bucket; LDS fp32 tile.
__global__ __launch_bounds__(256) void bucket_agg_kernel(
    const __hip_bfloat16* __restrict__ a, float* __restrict__ h,
    const int2* __restrict__ perm, const int* __restrict__ gcur) {
    __shared__ float acc[BN * 64];
    int b = blockIdx.x, tid = threadIdx.x;
    for (int i = tid; i < BN * 64; i += 256) acc[i] = 0.f;
    __syncthreads();
    int n = min(gcur[b], CAP);
    int lane = tid & 63, w = tid >> 6;
    const int2* ep = perm + (size_t)b * CAP;
    for (int base = w * 64; base < n; base += 256) {
        int cnt = min(64, n - base);
        int2 rec = (lane < cnt) ? ep[base + lane] : make_int2(0, 0);
        for (int t = 0; t < cnt; ++t) {
            int pk = __shfl(rec.x, t, 64);
            float e = __int_as_float(__shfl(rec.y, t, 64));
            int src = pk & 0xFFFFF;
            int dl = pk >> 20;
            float v = b2f(a[(size_t)src * 64 + lane]);
            atomicAdd(&acc[dl * 64 + lane], e * v);
        }
    }
    __syncthreads();
    size_t hb = (size_t)b * BN * 64;
    for (int i = tid; i < BN * 64; i += 256) {
        h[hb + i] = fmaxf(h[hb + i] + acc[i], 0.f);
    }
}

// ---------------- pooling + MLP ----------------

__global__ __launch_bounds__(256) void pool_kernel(const float* __restrict__ h,
                                                   const int* __restrict__ batch,
                                                   float* __restrict__ gx) {
    __shared__ int lohi[2];
    __shared__ float red[4][64];
    int g = blockIdx.x;
    if (threadIdx.x < 2) {
        int target = g + threadIdx.x;
        int lo = 0, hi = NNODES;
        while (lo < hi) { int m = (lo + hi) >> 1; if (batch[m] < target) lo = m + 1; else hi = m; }
        lohi[threadIdx.x] = lo;
    }
    __syncthreads();
    int lo = lohi[0], hi = lohi[1];
    int lane = threadIdx.x & 63, w = threadIdx.x >> 6;
    float sum = 0.f;
    for (int n = lo + w; n < hi; n += 4) sum += h[(size_t)n * 64 + lane];
    red[w][lane] = sum;
    __syncthreads();
    if (w == 0) {
        float tot = red[0][lane] + red[1][lane] + red[2][lane] + red[3][lane];
        int cnt = hi - lo;
        gx[g * 64 + lane] = tot / (float)max(cnt, 1);
    }
}

__global__ __launch_bounds__(64) void mlp_kernel(const float* __restrict__ gx,
                                                 const float* __restrict__ Wl1,
                                                 const float* __restrict__ bl1,
                                                 const float* __restrict__ Wl2,
                                                 const float* __restrict__ bl2,
                                                 float* __restrict__ out) {
    __shared__ float gxl[64];
    __shared__ float hid[32];
    int g = blockIdx.x, t = threadIdx.x;
    gxl[t] = gx[g * 64 + t];
    __syncthreads();
    if (t < 32) {
        float s = bl1[t];
        for (int k = 0; k < 64; ++k) s = fmaf(gxl[k], Wl1[k * 32 + t], s);
        hid[t] = fmaxf(s, 0.f);
    }
    __syncthreads();
    if (t < 3) {
        float s = bl2[t];
        for (int k = 0; k < 32; ++k) s = fmaf(hid[k], Wl2[k * 3 + t], s);
        out[g * 3 + t] = s;
    }
}

// ---------------- launch ----------------

extern "C" void kernel_launch(void* const* d_in, const int* in_sizes, int n_in,
                              void* d_out, int out_size, void* d_ws, size_t ws_size,
                              hipStream_t stream) {
    const float* x    = (const float*)d_in[0];
    const int*   ei   = (const int*)d_in[1];
    const float* ea   = (const float*)d_in[2];
    const int*   bat  = (const int*)d_in[3];
    const float* Wemb = (const float*)d_in[4];
    const float* bemb = (const float*)d_in[5];
    const float* W1   = (const float*)d_in[6];
    const float* b1   = (const float*)d_in[7];
    const float* W2   = (const float*)d_in[8];
    const float* W3   = (const float*)d_in[9];
    const float* b3   = (const float*)d_in[10];
    const float* Wl1  = (const float*)d_in[11];
    const float* bl1  = (const float*)d_in[12];
    const float* Wl2  = (const float*)d_in[13];
    const float* bl2  = (const float*)d_in[14];
    float* out = (float*)d_out;

    char* ws = (char*)d_ws;
    float*           h    = (float*)          (ws + 0);           // 25,600,000 B
    __hip_bfloat16*  a    = (__hip_bfloat16*) (ws + 25600000);    // 12,800,000 B
    int2*            perm = (int2*)           (ws + 38400000);    // 16,384,000 B
    int*             gcur = (int*)            (ws + 54784000);    //      4,096 B
    float*           wdeg = (float*)          (ws + 54788096);    //    400,000 B
    float*           gx   = (float*)          (ws + 55188096);    //    131,072 B -> ~55.3 MB

    zero_gcur_kernel<<<1, 1024, 0, stream>>>(gcur);
    bucket_scatter_kernel<<<SC_BLOCKS, 256, 0, stream>>>(ei, ea, gcur, perm);
    wdeg_kernel<<<NB, 256, 0, stream>>>(perm, gcur, wdeg);

    embed_kernel<<<NNODES * 64 / 256, 256, 0, stream>>>(x, Wemb, bemb, h);
    for (int l = 0; l < NLAYER; ++l) {
        gemm3_kernel<<<(NNODES + 63) / 64, 256, 0, stream>>>(
            h, wdeg, W1 + l * 4096, b1 + l * 64, W2 + l * 4096, W3 + l * 4096, b3 + l * 64, a);
        bucket_agg_kernel<<<NB, 256, 0, stream>>>(a, h, perm, gcur);
    }
    pool_kernel<<<NGRAPH, 256, 0, stream>>>(h, bat, gx);
    mlp_kernel<<<NGRAPH, 64, 0, stream>>>(gx, Wl1, bl1, Wl2, bl2, out);
}

// Round 4
// 820.012 us; speedup vs baseline: 2.8122x; 2.8122x over previous
//
#include <hip/hip_runtime.h>
#include <hip/hip_bf16.h>

#define NNODES 100000
#define NEDGES 1600000
#define NGRAPH 512
#define DIM    64
#define NLAYER 3

#define NB   1000   // buckets
#define BN   100    // nodes per bucket (NB*BN == NNODES exactly)
#define CAP  2048   // max edges per bucket (mean 1600, sigma ~40 -> +11 sigma)
#define SC_BLOCKS 200
#define EPB  8000   // edges per scatter block (SC_BLOCKS*EPB == NEDGES)

__device__ __forceinline__ float b2f(__hip_bfloat16 v) { return __bfloat162float(v); }

// ---------------- bucket build ----------------

__global__ void zero_gcur_kernel(int* __restrict__ gcur) {
    int i = threadIdx.x;
    if (i < NB) gcur[i] = 0;
}

// Edges -> 1000 coarse buckets by dst/100. Per-block LDS histogram, one global
// atomic per (block,bin) to reserve a contiguous region, then ranked scatter of
// packed records {src | dst_local<<20, e_bits}.
__global__ __launch_bounds__(256) void bucket_scatter_kernel(
    const int* __restrict__ ei, const float* __restrict__ ea,
    int* __restrict__ gcur, int2* __restrict__ perm_raw) {
    __shared__ int cnt_l[NB];
    __shared__ int cur_l[NB];
    int tid = threadIdx.x;
    int e0 = blockIdx.x * EPB;
    for (int i = tid; i < NB; i += 256) cnt_l[i] = 0;
    __syncthreads();
    for (int i = tid; i < EPB; i += 256) {
        int d = ei[NEDGES + e0 + i];
        atomicAdd(&cnt_l[d / BN], 1);
    }
    __syncthreads();
    for (int i = tid; i < NB; i += 256) {
        int c = cnt_l[i];
        cur_l[i] = (c > 0) ? atomicAdd(&gcur[i], c) : 0;
    }
    __syncthreads();
    for (int i = tid; i < EPB; i += 256) {
        int e = e0 + i;
        int s = ei[e];
        int d = ei[NEDGES + e];
        float w = ea[e];
        int bin = d / BN;
        int dloc = d - bin * BN;
        int r = atomicAdd(&cur_l[bin], 1);
        if (r < CAP)
            perm_raw[(size_t)bin * CAP + r] = make_int2(s | (dloc << 20), __float_as_int(w));
    }
}

// One block per bucket: LDS-stage records, counting-sort by local dst into an
// exact CSR (rows[node] = {start,end} into perm2), fusing wdeg computation.
__global__ __launch_bounds__(256) void bucket_csr_kernel(
    const int2* __restrict__ perm_raw, const int* __restrict__ gcur,
    int2* __restrict__ perm2, int2* __restrict__ rows, float* __restrict__ wdeg) {
    __shared__ int2  recs[CAP];      // 16 KB
    __shared__ int   cnt[BN];
    __shared__ int   start[BN];
    __shared__ int   cur[BN];
    __shared__ float ws[BN];
    int b = blockIdx.x, tid = threadIdx.x;
    if (tid < BN) { cnt[tid] = 0; ws[tid] = 0.f; }
    __syncthreads();
    int n = min(gcur[b], CAP);
    const int2* ep = perm_raw + (size_t)b * CAP;
    for (int i = tid; i < n; i += 256) {
        int2 rec = ep[i];
        recs[i] = rec;
        atomicAdd(&cnt[rec.x >> 20], 1);
        atomicAdd(&ws[rec.x >> 20], __int_as_float(rec.y));
    }
    __syncthreads();
    if (tid == 0) {
        int acc = 0;
        for (int i = 0; i < BN; ++i) { start[i] = acc; acc += cnt[i]; }
    }
    __syncthreads();
    if (tid < BN) {
        cur[tid] = start[tid];
        int base = b * CAP + start[tid];
        rows[b * BN + tid] = make_int2(base, base + cnt[tid]);
        wdeg[b * BN + tid] = ws[tid];
    }
    __syncthreads();
    for (int i = tid; i < n; i += 256) {
        int2 rec = recs[i];
        int dl = rec.x >> 20;
        int pos = atomicAdd(&cur[dl], 1);
        perm2[(size_t)b * CAP + pos] = make_int2(rec.x & 0xFFFFF, rec.y);
    }
}

// ---------------- dense ----------------

__global__ void embed_kernel(const float* __restrict__ x,
                             const float* __restrict__ W,
                             const float* __restrict__ b,
                             float* __restrict__ h) {
    int gid = blockIdx.x * 256 + threadIdx.x;
    if (gid >= NNODES * 64) return;
    int n = gid >> 6, cch = gid & 63;
    float s = b[cch];
    #pragma unroll
    for (int k = 0; k < 4; ++k) s = fmaf(x[n * 4 + k], W[k * 64 + cch], s);
    h[gid] = s;
}

// a_bf = bf16(h@W1 + b1) ; h <- h@W3 + b3 - wdeg*(h@W2)   (in-place c; safe:
// each 16-row group is read fully before its stores, only by its own wave)
__global__ __launch_bounds__(256) void gemm3_kernel(
    float* __restrict__ h, const float* __restrict__ wdeg,
    const float* __restrict__ W1, const float* __restrict__ b1,
    const float* __restrict__ W2,
    const float* __restrict__ W3, const float* __restrict__ b3,
    __hip_bfloat16* __restrict__ a) {
    __shared__ float w1s[4096], w2s[4096], w3s[4096];
    __shared__ float b1s[64], b3s[64];
    int tid = threadIdx.x;
    for (int i = tid; i < 4096; i += 256) {
        w1s[i] = W1[i]; w2s[i] = W2[i]; w3s[i] = W3[i];
    }
    if (tid < 64) { b1s[tid] = b1[tid]; b3s[tid] = b3[tid]; }
    __syncthreads();
    const int cch = tid & 63;
    const int sub = tid >> 6;
    int n0 = blockIdx.x * 64 + sub * 16;
    if (n0 >= NNODES) return;
    int nv = min(16, NNODES - n0);
    float acc1[16] = {0.f}, acc2[16] = {0.f}, acc3[16] = {0.f};
    float* hrow = h + (size_t)n0 * 64;
    for (int k = 0; k < 64; ++k) {
        float w1v = w1s[k * 64 + cch];
        float w2v = w2s[k * 64 + cch];
        float w3v = w3s[k * 64 + cch];
        #pragma unroll
        for (int j = 0; j < 16; ++j) {
            if (j < nv) {
                float hv = hrow[j * 64 + k];
                acc1[j] = fmaf(hv, w1v, acc1[j]);
                acc2[j] = fmaf(hv, w2v, acc2[j]);
                acc3[j] = fmaf(hv, w3v, acc3[j]);
            }
        }
    }
    #pragma unroll
    for (int j = 0; j < 16; ++j) {
        if (j < nv) {
            int n = n0 + j;
            a[(size_t)n * 64 + cch] = __float2bfloat16(acc1[j] + b1s[cch]);
            hrow[(size_t)j * 64 + cch] = acc3[j] + b3s[cch] - wdeg[n] * acc2[j];
        }
    }
}

// h = relu(h + sum_{edges into node} e * a[src])  -- one wave per node, lane = channel
__global__ __launch_bounds__(256) void edge_agg_kernel(
    const __hip_bfloat16* __restrict__ a, float* __restrict__ h,
    const int2* __restrict__ rows, const int2* __restrict__ perm2) {
    int node = blockIdx.x * 4 + (threadIdx.x >> 6);
    if (node >= NNODES) return;
    int lane = threadIdx.x & 63;
    int2 r = rows[node];           // wave-uniform broadcast load
    int start = r.x, end = r.y;
    float acc = h[(size_t)node * 64 + lane];
    for (int b = start; b < end; b += 64) {
        int cnt = min(64, end - b);
        int2 rec = (lane < cnt) ? perm2[b + lane] : make_int2(0, 0);
        for (int t = 0; t < cnt; ++t) {
            int src = __shfl(rec.x, t, 64);
            float e = __int_as_float(__shfl(rec.y, t, 64));
            acc = fmaf(e, b2f(a[(size_t)src * 64 + lane]), acc);
        }
    }
    h[(size_t)node * 64 + lane] = fmaxf(acc, 0.f);
}

// ---------------- pooling + MLP ----------------

__global__ __launch_bounds__(256) void pool_kernel(const float* __restrict__ h,
                                                   const int* __restrict__ batch,
                                                   float* __restrict__ gx) {
    __shared__ int lohi[2];
    __shared__ float red[4][64];
    int g = blockIdx.x;
    if (threadIdx.x < 2) {
        int target = g + threadIdx.x;
        int lo = 0, hi = NNODES;
        while (lo < hi) { int m = (lo + hi) >> 1; if (batch[m] < target) lo = m + 1; else hi = m; }
        lohi[threadIdx.x] = lo;
    }
    __syncthreads();
    int lo = lohi[0], hi = lohi[1];
    int lane = threadIdx.x & 63, w = threadIdx.x >> 6;
    float sum = 0.f;
    for (int n = lo + w; n < hi; n += 4) sum += h[(size_t)n * 64 + lane];
    red[w][lane] = sum;
    __syncthreads();
    if (w == 0) {
        float tot = red[0][lane] + red[1][lane] + red[2][lane] + red[3][lane];
        int cnt = hi - lo;
        gx[g * 64 + lane] = tot / (float)max(cnt, 1);
    }
}

__global__ __launch_bounds__(64) void mlp_kernel(const float* __restrict__ gx,
                                                 const float* __restrict__ Wl1,
                                                 const float* __restrict__ bl1,
                                                 const float* __restrict__ Wl2,
                                                 const float* __restrict__ bl2,
                                                 float* __restrict__ out) {
    __shared__ float gxl[64];
    __shared__ float hid[32];
    int g = blockIdx.x, t = threadIdx.x;
    gxl[t] = gx[g * 64 + t];
    __syncthreads();
    if (t < 32) {
        float s = bl1[t];
        for (int k = 0; k < 64; ++k) s = fmaf(gxl[k], Wl1[k * 32 + t], s);
        hid[t] = fmaxf(s, 0.f);
    }
    __syncthreads();
    if (t < 3) {
        float s = bl2[t];
        for (int k = 0; k < 32; ++k) s = fmaf(hid[k], Wl2[k * 3 + t], s);
        out[g * 3 + t] = s;
    }
}

// ---------------- launch ----------------

extern "C" void kernel_launch(void* const* d_in, const int* in_sizes, int n_in,
                              void* d_out, int out_size, void* d_ws, size_t ws_size,
                              hipStream_t stream) {
    const float* x    = (const float*)d_in[0];
    const int*   ei   = (const int*)d_in[1];
    const float* ea   = (const float*)d_in[2];
    const int*   bat  = (const int*)d_in[3];
    const float* Wemb = (const float*)d_in[4];
    const float* bemb = (const float*)d_in[5];
    const float* W1   = (const float*)d_in[6];
    const float* b1   = (const float*)d_in[7];
    const float* W2   = (const float*)d_in[8];
    const float* W3   = (const float*)d_in[9];
    const float* b3   = (const float*)d_in[10];
    const float* Wl1  = (const float*)d_in[11];
    const float* bl1  = (const float*)d_in[12];
    const float* Wl2  = (const float*)d_in[13];
    const float* bl2  = (const float*)d_in[14];
    float* out = (float*)d_out;

    char* ws = (char*)d_ws;
    float*           h        = (float*)          (ws + 0);           // 25,600,000 B
    __hip_bfloat16*  a        = (__hip_bfloat16*) (ws + 25600000);    // 12,800,000 B
    int2*            perm_raw = (int2*)           (ws + 38400000);    // 16,384,000 B
    int2*            perm2    = (int2*)           (ws + 54784000);    // 16,384,000 B
    int2*            rows     = (int2*)           (ws + 71168000);    //    800,000 B
    int*             gcur     = (int*)            (ws + 71968000);    //      4,096 B
    float*           wdeg     = (float*)          (ws + 71972096);    //    400,000 B
    float*           gx       = (float*)          (ws + 72372096);    //    131,072 B -> ~72.5 MB

    zero_gcur_kernel<<<1, 1024, 0, stream>>>(gcur);
    bucket_scatter_kernel<<<SC_BLOCKS, 256, 0, stream>>>(ei, ea, gcur, perm_raw);
    bucket_csr_kernel<<<NB, 256, 0, stream>>>(perm_raw, gcur, perm2, rows, wdeg);

    embed_kernel<<<NNODES * 64 / 256, 256, 0, stream>>>(x, Wemb, bemb, h);
    for (int l = 0; l < NLAYER; ++l) {
        gemm3_kernel<<<(NNODES + 63) / 64, 256, 0, stream>>>(
            h, wdeg, W1 + l * 4096, b1 + l * 64, W2 + l * 4096, W3 + l * 4096, b3 + l * 64, a);
        edge_agg_kernel<<<(NNODES + 3) / 4, 256, 0, stream>>>(a, h, rows, perm2);
    }
    pool_kernel<<<NGRAPH, 256, 0, stream>>>(h, bat, gx);
    mlp_kernel<<<NGRAPH, 64, 0, stream>>>(gx, Wl1, bl1, Wl2, bl2, out);
}

// Round 5
// 381.927 us; speedup vs baseline: 6.0380x; 2.1470x over previous
//
#include <hip/hip_runtime.h>
#include <hip/hip_bf16.h>

#define NNODES 100000
#define NEDGES 1600000
#define NGRAPH 512
#define DIM    64
#define NLAYER 3

#define NB   1000   // buckets
#define BN   100    // nodes per bucket (NB*BN == NNODES exactly)
#define CAP  2048   // max edges per bucket (mean 1600, sigma ~40)
#define SC_BLOCKS 200
#define EPB  8000   // edges per scatter block

typedef __attribute__((ext_vector_type(8))) short short8;
typedef __attribute__((ext_vector_type(4))) float float4v;

__device__ __forceinline__ float b2f(__hip_bfloat16 v) { return __bfloat162float(v); }
__device__ __forceinline__ __hip_bfloat16 f2b(float f) { return __float2bfloat16(f); }

// ---------------- bucket build ----------------

__global__ void zero_gcur_kernel(int* __restrict__ gcur) {
    int i = threadIdx.x;
    if (i < NB) gcur[i] = 0;
}

__global__ __launch_bounds__(256) void bucket_scatter_kernel(
    const int* __restrict__ ei, const float* __restrict__ ea,
    int* __restrict__ gcur, int2* __restrict__ perm_raw) {
    __shared__ int cnt_l[NB];
    __shared__ int cur_l[NB];
    int tid = threadIdx.x;
    int e0 = blockIdx.x * EPB;
    for (int i = tid; i < NB; i += 256) cnt_l[i] = 0;
    __syncthreads();
    for (int i = tid; i < EPB; i += 256) {
        int d = ei[NEDGES + e0 + i];
        atomicAdd(&cnt_l[d / BN], 1);
    }
    __syncthreads();
    for (int i = tid; i < NB; i += 256) {
        int c = cnt_l[i];
        cur_l[i] = (c > 0) ? atomicAdd(&gcur[i], c) : 0;
    }
    __syncthreads();
    for (int i = tid; i < EPB; i += 256) {
        int e = e0 + i;
        int s = ei[e];
        int d = ei[NEDGES + e];
        float w = ea[e];
        int bin = d / BN;
        int dloc = d - bin * BN;
        int r = atomicAdd(&cur_l[bin], 1);
        if (r < CAP)
            perm_raw[(size_t)bin * CAP + r] = make_int2(s | (dloc << 20), __float_as_int(w));
    }
}

// In-place counting sort per bucket (perm_out may alias perm_in: all reads are
// LDS-staged and fenced by __syncthreads before any write).
__global__ __launch_bounds__(256) void bucket_csr_kernel(
    const int2* perm_in, const int* __restrict__ gcur,
    int2* perm_out, int2* __restrict__ rows, float* __restrict__ wdeg) {
    __shared__ int2  recs[CAP];      // 16 KB
    __shared__ int   cnt[BN];
    __shared__ int   start[BN];
    __shared__ int   cur[BN];
    __shared__ float ws[BN];
    int b = blockIdx.x, tid = threadIdx.x;
    if (tid < BN) { cnt[tid] = 0; ws[tid] = 0.f; }
    __syncthreads();
    int n = min(gcur[b], CAP);
    const int2* ep = perm_in + (size_t)b * CAP;
    for (int i = tid; i < n; i += 256) {
        int2 rec = ep[i];
        recs[i] = rec;
        atomicAdd(&cnt[rec.x >> 20], 1);
        atomicAdd(&ws[rec.x >> 20], __int_as_float(rec.y));
    }
    __syncthreads();
    if (tid == 0) {
        int acc = 0;
        for (int i = 0; i < BN; ++i) { start[i] = acc; acc += cnt[i]; }
    }
    __syncthreads();
    if (tid < BN) {
        cur[tid] = start[tid];
        int base = b * CAP + start[tid];
        rows[b * BN + tid] = make_int2(base, base + cnt[tid]);
        wdeg[b * BN + tid] = ws[tid];
    }
    __syncthreads();
    for (int i = tid; i < n; i += 256) {
        int2 rec = recs[i];
        int dl = rec.x >> 20;
        int pos = atomicAdd(&cur[dl], 1);
        perm_out[(size_t)b * CAP + pos] = make_int2(rec.x & 0xFFFFF, rec.y);
    }
}

// ---------------- weight pre-pack (fp32 -> bf16 B-fragment order) ----------------
// One block per (l, w, tn, kh); frag element: lane L, j ->
//   W[32*kh + (L>>4)*8 + j][16*tn + (L&15)]
__global__ __launch_bounds__(64) void pack_w_kernel(
    const float* __restrict__ W1, const float* __restrict__ W2,
    const float* __restrict__ W3, __hip_bfloat16* __restrict__ wpack) {
    int b = blockIdx.x;
    int kh = b & 1, tn = (b >> 1) & 3, w = (b >> 3) % 3, l = b / 24;
    const float* Wsrc = (w == 0 ? W1 : (w == 1 ? W2 : W3)) + l * 4096;
    int L = threadIdx.x;
    __hip_bfloat16* dst = wpack + (size_t)b * 512 + L * 8;
    int kb = 32 * kh + (L >> 4) * 8;
    int nb = 16 * tn + (L & 15);
    #pragma unroll
    for (int j = 0; j < 8; ++j)
        dst[j] = f2b(Wsrc[(kb + j) * 64 + nb]);
}

// ---------------- dense ----------------

__global__ void embed_kernel(const float* __restrict__ x,
                             const float* __restrict__ W,
                             const float* __restrict__ b,
                             __hip_bfloat16* __restrict__ h16) {
    int gid = blockIdx.x * 256 + threadIdx.x;
    if (gid >= NNODES * 64) return;
    int n = gid >> 6, cch = gid & 63;
    float s = b[cch];
    #pragma unroll
    for (int k = 0; k < 4; ++k) s = fmaf(x[n * 4 + k], W[k * 64 + cch], s);
    h16[gid] = f2b(s);
}

// MFMA: a = bf16(h@W1+b1) ; c = h@W3+b3 - wdeg*(h@W2)  (fp32)
// Block = 4 waves, 64 nodes; wave = 16 nodes x 64 ch.
__global__ __launch_bounds__(256) void gemm3_mfma_kernel(
    const __hip_bfloat16* __restrict__ h16, const float* __restrict__ wdeg,
    const __hip_bfloat16* __restrict__ wpack,   // layer slice: 3*4*2*512 bf16
    const float* __restrict__ b1, const float* __restrict__ b3,
    __hip_bfloat16* __restrict__ a, float* __restrict__ c) {
    int tid = threadIdx.x;
    int lane = tid & 63, wv = tid >> 6;
    int m0 = blockIdx.x * 64 + wv * 16;
    int q = lane >> 4;
    int node_a = m0 + (lane & 15);
    int node_c = min(node_a, NNODES - 1);

    float4v acc[3][4] = {};
    const short8* wp = (const short8*)wpack;   // [ (w*4+tn)*2+kh ][lane]

    #pragma unroll
    for (int kh = 0; kh < 2; ++kh) {
        short8 afrag = *(const short8*)((const short*)h16 + (size_t)node_c * 64 + kh * 32 + q * 8);
        #pragma unroll
        for (int w = 0; w < 3; ++w) {
            #pragma unroll
            for (int tn = 0; tn < 4; ++tn) {
                short8 bfrag = wp[(size_t)(((w * 4 + tn) * 2 + kh)) * 64 + lane];
                acc[w][tn] = __builtin_amdgcn_mfma_f32_16x16x32_bf16(afrag, bfrag, acc[w][tn], 0, 0, 0);
            }
        }
    }

    // epilogue: C/D layout col=lane&15, row=q*4+reg
    int coll = lane & 15;
    float b1v[4], b3v[4];
    #pragma unroll
    for (int tn = 0; tn < 4; ++tn) {
        b1v[tn] = b1[tn * 16 + coll];
        b3v[tn] = b3[tn * 16 + coll];
    }
    #pragma unroll
    for (int reg = 0; reg < 4; ++reg) {
        int node = m0 + q * 4 + reg;
        if (node < NNODES) {
            float wd = wdeg[node];
            #pragma unroll
            for (int tn = 0; tn < 4; ++tn) {
                int nn = tn * 16 + coll;
                a[(size_t)node * 64 + nn] = f2b(acc[0][tn][reg] + b1v[tn]);
                c[(size_t)node * 64 + nn] = acc[2][tn][reg] + b3v[tn] - wd * acc[1][tn][reg];
            }
        }
    }
}

// h16 = bf16(relu(c + sum_{edges} e * a[src]))  -- one wave per node, lane = channel
__global__ __launch_bounds__(256) void edge_agg_kernel(
    const __hip_bfloat16* __restrict__ a, const float* __restrict__ c,
    __hip_bfloat16* __restrict__ h16,
    const int2* __restrict__ rows, const int2* __restrict__ perm2) {
    int node = blockIdx.x * 4 + (threadIdx.x >> 6);
    if (node >= NNODES) return;
    int lane = threadIdx.x & 63;
    int2 r = rows[node];
    int start = r.x, end = r.y;
    float base_v = c[(size_t)node * 64 + lane];
    float a0 = 0.f, a1 = 0.f, a2 = 0.f, a3 = 0.f;
    for (int b = start; b < end; b += 64) {
        int cnt = min(64, end - b);
        int2 rec = (lane < cnt) ? perm2[b + lane] : make_int2(0, 0);
        int t = 0;
        for (; t + 3 < cnt; t += 4) {
            int s0 = __shfl(rec.x, t, 64);     float e0 = __int_as_float(__shfl(rec.y, t, 64));
            int s1 = __shfl(rec.x, t + 1, 64); float e1 = __int_as_float(__shfl(rec.y, t + 1, 64));
            int s2 = __shfl(rec.x, t + 2, 64); float e2 = __int_as_float(__shfl(rec.y, t + 2, 64));
            int s3 = __shfl(rec.x, t + 3, 64); float e3 = __int_as_float(__shfl(rec.y, t + 3, 64));
            float v0 = b2f(a[(size_t)s0 * 64 + lane]);
            float v1 = b2f(a[(size_t)s1 * 64 + lane]);
            float v2 = b2f(a[(size_t)s2 * 64 + lane]);
            float v3 = b2f(a[(size_t)s3 * 64 + lane]);
            a0 = fmaf(e0, v0, a0);
            a1 = fmaf(e1, v1, a1);
            a2 = fmaf(e2, v2, a2);
            a3 = fmaf(e3, v3, a3);
        }
        for (; t < cnt; ++t) {
            int s = __shfl(rec.x, t, 64);
            float e = __int_as_float(__shfl(rec.y, t, 64));
            a0 = fmaf(e, b2f(a[(size_t)s * 64 + lane]), a0);
        }
    }
    float res = base_v + ((a0 + a1) + (a2 + a3));
    h16[(size_t)node * 64 + lane] = f2b(fmaxf(res, 0.f));
}

// ---------------- pooling + MLP ----------------

__global__ __launch_bounds__(256) void pool_kernel(const __hip_bfloat16* __restrict__ h16,
                                                   const int* __restrict__ batch,
                                                   float* __restrict__ gx) {
    __shared__ int lohi[2];
    __shared__ float red[4][64];
    int g = blockIdx.x;
    if (threadIdx.x < 2) {
        int target = g + threadIdx.x;
        int lo = 0, hi = NNODES;
        while (lo < hi) { int m = (lo + hi) >> 1; if (batch[m] < target) lo = m + 1; else hi = m; }
        lohi[threadIdx.x] = lo;
    }
    __syncthreads();
    int lo = lohi[0], hi = lohi[1];
    int lane = threadIdx.x & 63, w = threadIdx.x >> 6;
    float sum = 0.f;
    for (int n = lo + w; n < hi; n += 4) sum += b2f(h16[(size_t)n * 64 + lane]);
    red[w][lane] = sum;
    __syncthreads();
    if (w == 0) {
        float tot = red[0][lane] + red[1][lane] + red[2][lane] + red[3][lane];
        int cnt = hi - lo;
        gx[g * 64 + lane] = tot / (float)max(cnt, 1);
    }
}

__global__ __launch_bounds__(64) void mlp_kernel(const float* __restrict__ gx,
                                                 const float* __restrict__ Wl1,
                                                 const float* __restrict__ bl1,
                                                 const float* __restrict__ Wl2,
                                                 const float* __restrict__ bl2,
                                                 float* __restrict__ out) {
    __shared__ float gxl[64];
    __shared__ float hid[32];
    int g = blockIdx.x, t = threadIdx.x;
    gxl[t] = gx[g * 64 + t];
    __syncthreads();
    if (t < 32) {
        float s = bl1[t];
        for (int k = 0; k < 64; ++k) s = fmaf(gxl[k], Wl1[k * 32 + t], s);
        hid[t] = fmaxf(s, 0.f);
    }
    __syncthreads();
    if (t < 3) {
        float s = bl2[t];
        for (int k = 0; k < 32; ++k) s = fmaf(hid[k], Wl2[k * 3 + t], s);
        out[g * 3 + t] = s;
    }
}

// ---------------- launch ----------------

extern "C" void kernel_launch(void* const* d_in, const int* in_sizes, int n_in,
                              void* d_out, int out_size, void* d_ws, size_t ws_size,
                              hipStream_t stream) {
    const float* x    = (const float*)d_in[0];
    const int*   ei   = (const int*)d_in[1];
    const float* ea   = (const float*)d_in[2];
    const int*   bat  = (const int*)d_in[3];
    const float* Wemb = (const float*)d_in[4];
    const float* bemb = (const float*)d_in[5];
    const float* W1   = (const float*)d_in[6];
    const float* b1   = (const float*)d_in[7];
    const float* W2   = (const float*)d_in[8];
    const float* W3   = (const float*)d_in[9];
    const float* b3   = (const float*)d_in[10];
    const float* Wl1  = (const float*)d_in[11];
    const float* bl1  = (const float*)d_in[12];
    const float* Wl2  = (const float*)d_in[13];
    const float* bl2  = (const float*)d_in[14];
    float* out = (float*)d_out;

    char* ws = (char*)d_ws;
    float*           c     = (float*)          (ws + 0);           // 25,600,000
    __hip_bfloat16*  a     = (__hip_bfloat16*) (ws + 25600000);    // 12,800,000
    __hip_bfloat16*  h16   = (__hip_bfloat16*) (ws + 38400000);    // 12,800,000
    int2*            perm  = (int2*)           (ws + 51200000);    // 16,384,000 (raw then CSR, in-place)
    int2*            rows  = (int2*)           (ws + 67584000);    //    800,000
    int*             gcur  = (int*)            (ws + 68384000);    //      4,096
    float*           wdeg  = (float*)          (ws + 68388096);    //    400,000
    float*           gx    = (float*)          (ws + 68788096);    //    131,072
    __hip_bfloat16*  wpack = (__hip_bfloat16*) (ws + 68919168);    //     73,728 -> ~69.0 MB

    zero_gcur_kernel<<<1, 1024, 0, stream>>>(gcur);
    bucket_scatter_kernel<<<SC_BLOCKS, 256, 0, stream>>>(ei, ea, gcur, perm);
    bucket_csr_kernel<<<NB, 256, 0, stream>>>(perm, gcur, perm, rows, wdeg);
    pack_w_kernel<<<NLAYER * 24, 64, 0, stream>>>(W1, W2, W3, wpack);

    embed_kernel<<<NNODES * 64 / 256, 256, 0, stream>>>(x, Wemb, bemb, h16);
    for (int l = 0; l < NLAYER; ++l) {
        gemm3_mfma_kernel<<<(NNODES + 63) / 64, 256, 0, stream>>>(
            h16, wdeg, wpack + (size_t)l * 24 * 512, b1 + l * 64, b3 + l * 64, a, c);
        edge_agg_kernel<<<(NNODES + 3) / 4, 256, 0, stream>>>(a, c, h16, rows, perm);
    }
    pool_kernel<<<NGRAPH, 256, 0, stream>>>(h16, bat, gx);
    mlp_kernel<<<NGRAPH, 64, 0, stream>>>(gx, Wl1, bl1, Wl2, bl2, out);
}

// Round 6
// 364.419 us; speedup vs baseline: 6.3281x; 1.0480x over previous
//
#include <hip/hip_runtime.h>
#include <hip/hip_bf16.h>

#define NNODES 100000
#define NEDGES 1600000
#define NGRAPH 512
#define DIM    64
#define NLAYER 3

#define NB   1000   // buckets
#define BN   100    // nodes per bucket (NB*BN == NNODES exactly)
#define CAP  2048   // max edges per bucket (mean 1600, sigma ~40)
#define SC_BLOCKS 256
#define EPB  6250   // edges per sort block (SC_BLOCKS*EPB == NEDGES)

typedef __attribute__((ext_vector_type(8))) short short8;
typedef __attribute__((ext_vector_type(4))) float float4v;

__device__ __forceinline__ float b2f(__hip_bfloat16 v) { return __bfloat162float(v); }
__device__ __forceinline__ __hip_bfloat16 f2b(float f) { return __float2bfloat16(f); }

// ---------------- CSR build: deterministic two-level sort, no global atomics ----

// Block k sorts its 6250 edges by bucket into perm_raw[k*EPB ..], publishes
// offcnt[k*NB+b] = {local offset, count}. All writes land in the block's dense
// private region -> L2 write-back coalesces to full lines.
__global__ __launch_bounds__(256) void local_sort_kernel(
    const int* __restrict__ ei, const float* __restrict__ ea,
    int2* __restrict__ perm_raw, int2* __restrict__ offcnt) {
    __shared__ int cnt[NB];
    __shared__ int off[NB];
    __shared__ int partial[256];
    int tid = threadIdx.x, k = blockIdx.x;
    int e0 = k * EPB;
    for (int i = tid; i < NB; i += 256) cnt[i] = 0;
    __syncthreads();
    for (int i = tid; i < EPB; i += 256)
        atomicAdd(&cnt[ei[NEDGES + e0 + i] / BN], 1);
    __syncthreads();
    // exclusive scan of cnt[1000]: thread t owns bins 4t..4t+3
    int loc[4]; int s = 0;
    #pragma unroll
    for (int j = 0; j < 4; ++j) {
        int b = tid * 4 + j;
        int v = (b < NB) ? cnt[b] : 0;
        loc[j] = s; s += v;
    }
    partial[tid] = s;
    __syncthreads();
    for (int o = 1; o < 256; o <<= 1) {
        int t = (tid >= o) ? partial[tid - o] : 0;
        __syncthreads();
        partial[tid] += t;
        __syncthreads();
    }
    int excl = partial[tid] - s;
    #pragma unroll
    for (int j = 0; j < 4; ++j) {
        int b = tid * 4 + j;
        if (b < NB) off[b] = excl + loc[j];
    }
    __syncthreads();
    for (int b = tid; b < NB; b += 256)
        offcnt[(size_t)k * NB + b] = make_int2(off[b], cnt[b]);
    __syncthreads();
    // ranked scatter into private dense region (off[] reused as cursor)
    for (int i = tid; i < EPB; i += 256) {
        int e = e0 + i;
        int src = ei[e];
        int d = ei[NEDGES + e];
        float w = ea[e];
        int bin = d / BN;
        int dloc = d - bin * BN;
        int pos = atomicAdd(&off[bin], 1);
        perm_raw[e0 + pos] = make_int2(src | (dloc << 20), __float_as_int(w));
    }
}

// One block per bucket: gather its records from the 256 block segments into
// LDS, counting-sort by local dst in LDS, write perm2 coalesced; fused wdeg.
__global__ __launch_bounds__(256) void bucket_csr_kernel(
    const int2* __restrict__ perm_raw, const int2* __restrict__ offcnt,
    int2* __restrict__ perm2, int2* __restrict__ rows, float* __restrict__ wdeg) {
    __shared__ int2  recs[CAP];           // 16 KB
    __shared__ int2  recs2[CAP];          // 16 KB
    __shared__ int   pscan[256];
    __shared__ int   sprefix[SC_BLOCKS + 1];
    __shared__ int   boff[SC_BLOCKS];
    __shared__ int   cnt[BN];
    __shared__ int   start[BN];
    __shared__ int   cur[BN];
    __shared__ float ws[BN];
    int b = blockIdx.x, tid = threadIdx.x;
    if (tid < BN) { cnt[tid] = 0; ws[tid] = 0.f; }
    int2 oc = offcnt[(size_t)tid * NB + b];
    boff[tid] = oc.x;
    int c = oc.y;
    pscan[tid] = c;
    __syncthreads();
    for (int o = 1; o < 256; o <<= 1) {
        int t = (tid >= o) ? pscan[tid - o] : 0;
        __syncthreads();
        pscan[tid] += t;
        __syncthreads();
    }
    sprefix[tid] = pscan[tid] - c;        // exclusive
    if (tid == 255) sprefix[256] = pscan[255];
    __syncthreads();
    int n = min(sprefix[SC_BLOCKS], CAP);
    for (int i = tid; i < n; i += 256) {
        int lo = 0, hi = SC_BLOCKS;       // sprefix[lo] <= i < sprefix[hi]
        while (hi - lo > 1) { int m = (lo + hi) >> 1; if (sprefix[m] <= i) lo = m; else hi = m; }
        int2 rec = perm_raw[lo * EPB + boff[lo] + (i - sprefix[lo])];
        recs[i] = rec;
        atomicAdd(&cnt[rec.x >> 20], 1);
        atomicAdd(&ws[rec.x >> 20], __int_as_float(rec.y));
    }
    __syncthreads();
    if (tid == 0) {
        int acc = 0;
        for (int i = 0; i < BN; ++i) { start[i] = acc; acc += cnt[i]; }
    }
    __syncthreads();
    if (tid < BN) {
        cur[tid] = start[tid];
        int base = b * CAP + start[tid];
        rows[b * BN + tid] = make_int2(base, base + cnt[tid]);
        wdeg[b * BN + tid] = ws[tid];
    }
    __syncthreads();
    for (int i = tid; i < n; i += 256) {
        int2 rec = recs[i];
        int pos = atomicAdd(&cur[rec.x >> 20], 1);
        recs2[pos] = make_int2(rec.x & 0xFFFFF, rec.y);
    }
    __syncthreads();
    for (int i = tid; i < n; i += 256)
        perm2[(size_t)b * CAP + i] = recs2[i];     // coalesced writeback
}

// ---------------- weight pre-pack (fp32 -> bf16 B-fragment order) ----------------

__global__ __launch_bounds__(64) void pack_w_kernel(
    const float* __restrict__ W1, const float* __restrict__ W2,
    const float* __restrict__ W3, __hip_bfloat16* __restrict__ wpack) {
    int b = blockIdx.x;
    int kh = b & 1, tn = (b >> 1) & 3, w = (b >> 3) % 3, l = b / 24;
    const float* Wsrc = (w == 0 ? W1 : (w == 1 ? W2 : W3)) + l * 4096;
    int L = threadIdx.x;
    __hip_bfloat16* dst = wpack + (size_t)b * 512 + L * 8;
    int kb = 32 * kh + (L >> 4) * 8;
    int nb = 16 * tn + (L & 15);
    #pragma unroll
    for (int j = 0; j < 8; ++j)
        dst[j] = f2b(Wsrc[(kb + j) * 64 + nb]);
}

// ---------------- dense ----------------

__global__ void embed_kernel(const float* __restrict__ x,
                             const float* __restrict__ W,
                             const float* __restrict__ b,
                             __hip_bfloat16* __restrict__ h16) {
    int gid = blockIdx.x * 256 + threadIdx.x;
    if (gid >= NNODES * 64) return;
    int n = gid >> 6, cch = gid & 63;
    float s = b[cch];
    #pragma unroll
    for (int k = 0; k < 4; ++k) s = fmaf(x[n * 4 + k], W[k * 64 + cch], s);
    h16[gid] = f2b(s);
}

// MFMA: a = bf16(h@W1+b1) ; c = h@W3+b3 - wdeg*(h@W2)  (fp32)
__global__ __launch_bounds__(256) void gemm3_mfma_kernel(
    const __hip_bfloat16* __restrict__ h16, const float* __restrict__ wdeg,
    const __hip_bfloat16* __restrict__ wpack,
    const float* __restrict__ b1, const float* __restrict__ b3,
    __hip_bfloat16* __restrict__ a, float* __restrict__ c) {
    int tid = threadIdx.x;
    int lane = tid & 63, wv = tid >> 6;
    int m0 = blockIdx.x * 64 + wv * 16;
    int q = lane >> 4;
    int node_a = m0 + (lane & 15);
    int node_c = min(node_a, NNODES - 1);

    float4v acc[3][4] = {};
    const short8* wp = (const short8*)wpack;

    #pragma unroll
    for (int kh = 0; kh < 2; ++kh) {
        short8 afrag = *(const short8*)((const short*)h16 + (size_t)node_c * 64 + kh * 32 + q * 8);
        #pragma unroll
        for (int w = 0; w < 3; ++w) {
            #pragma unroll
            for (int tn = 0; tn < 4; ++tn) {
                short8 bfrag = wp[(size_t)(((w * 4 + tn) * 2 + kh)) * 64 + lane];
                acc[w][tn] = __builtin_amdgcn_mfma_f32_16x16x32_bf16(afrag, bfrag, acc[w][tn], 0, 0, 0);
            }
        }
    }

    int coll = lane & 15;
    float b1v[4], b3v[4];
    #pragma unroll
    for (int tn = 0; tn < 4; ++tn) {
        b1v[tn] = b1[tn * 16 + coll];
        b3v[tn] = b3[tn * 16 + coll];
    }
    #pragma unroll
    for (int reg = 0; reg < 4; ++reg) {
        int node = m0 + q * 4 + reg;
        if (node < NNODES) {
            float wd = wdeg[node];
            #pragma unroll
            for (int tn = 0; tn < 4; ++tn) {
                int nn = tn * 16 + coll;
                a[(size_t)node * 64 + nn] = f2b(acc[0][tn][reg] + b1v[tn]);
                c[(size_t)node * 64 + nn] = acc[2][tn][reg] + b3v[tn] - wd * acc[1][tn][reg];
            }
        }
    }
}

// h16 = bf16(relu(c + sum_{edges} e * a[src]))  -- one wave per node, lane = channel
__global__ __launch_bounds__(256) void edge_agg_kernel(
    const __hip_bfloat16* __restrict__ a, const float* __restrict__ c,
    __hip_bfloat16* __restrict__ h16,
    const int2* __restrict__ rows, const int2* __restrict__ perm2) {
    int node = blockIdx.x * 4 + (threadIdx.x >> 6);
    if (node >= NNODES) return;
    int lane = threadIdx.x & 63;
    int2 r = rows[node];
    int start = r.x, end = r.y;
    float base_v = c[(size_t)node * 64 + lane];
    float a0 = 0.f, a1 = 0.f, a2 = 0.f, a3 = 0.f;
    for (int b = start; b < end; b += 64) {
        int cnt = min(64, end - b);
        int2 rec = (lane < cnt) ? perm2[b + lane] : make_int2(0, 0);
        int t = 0;
        for (; t + 3 < cnt; t += 4) {
            int s0 = __shfl(rec.x, t, 64);     float e0 = __int_as_float(__shfl(rec.y, t, 64));
            int s1 = __shfl(rec.x, t + 1, 64); float e1 = __int_as_float(__shfl(rec.y, t + 1, 64));
            int s2 = __shfl(rec.x, t + 2, 64); float e2 = __int_as_float(__shfl(rec.y, t + 2, 64));
            int s3 = __shfl(rec.x, t + 3, 64); float e3 = __int_as_float(__shfl(rec.y, t + 3, 64));
            float v0 = b2f(a[(size_t)s0 * 64 + lane]);
            float v1 = b2f(a[(size_t)s1 * 64 + lane]);
            float v2 = b2f(a[(size_t)s2 * 64 + lane]);
            float v3 = b2f(a[(size_t)s3 * 64 + lane]);
            a0 = fmaf(e0, v0, a0);
            a1 = fmaf(e1, v1, a1);
            a2 = fmaf(e2, v2, a2);
            a3 = fmaf(e3, v3, a3);
        }
        for (; t < cnt; ++t) {
            int s = __shfl(rec.x, t, 64);
            float e = __int_as_float(__shfl(rec.y, t, 64));
            a0 = fmaf(e, b2f(a[(size_t)s * 64 + lane]), a0);
        }
    }
    float res = base_v + ((a0 + a1) + (a2 + a3));
    h16[(size_t)node * 64 + lane] = f2b(fmaxf(res, 0.f));
}

// ---------------- pooling + MLP ----------------

__global__ __launch_bounds__(256) void pool_kernel(const __hip_bfloat16* __restrict__ h16,
                                                   const int* __restrict__ batch,
                                                   float* __restrict__ gx) {
    __shared__ int lohi[2];
    __shared__ float red[4][64];
    int g = blockIdx.x;
    if (threadIdx.x < 2) {
        int target = g + threadIdx.x;
        int lo = 0, hi = NNODES;
        while (lo < hi) { int m = (lo + hi) >> 1; if (batch[m] < target) lo = m + 1; else hi = m; }
        lohi[threadIdx.x] = lo;
    }
    __syncthreads();
    int lo = lohi[0], hi = lohi[1];
    int lane = threadIdx.x & 63, w = threadIdx.x >> 6;
    float sum = 0.f;
    for (int n = lo + w; n < hi; n += 4) sum += b2f(h16[(size_t)n * 64 + lane]);
    red[w][lane] = sum;
    __syncthreads();
    if (w == 0) {
        float tot = red[0][lane] + red[1][lane] + red[2][lane] + red[3][lane];
        int cnt = hi - lo;
        gx[g * 64 + lane] = tot / (float)max(cnt, 1);
    }
}

__global__ __launch_bounds__(64) void mlp_kernel(const float* __restrict__ gx,
                                                 const float* __restrict__ Wl1,
                                                 const float* __restrict__ bl1,
                                                 const float* __restrict__ Wl2,
                                                 const float* __restrict__ bl2,
                                                 float* __restrict__ out) {
    __shared__ float gxl[64];
    __shared__ float hid[32];
    int g = blockIdx.x, t = threadIdx.x;
    gxl[t] = gx[g * 64 + t];
    __syncthreads();
    if (t < 32) {
        float s = bl1[t];
        for (int k = 0; k < 64; ++k) s = fmaf(gxl[k], Wl1[k * 32 + t], s);
        hid[t] = fmaxf(s, 0.f);
    }
    __syncthreads();
    if (t < 3) {
        float s = bl2[t];
        for (int k = 0; k < 32; ++k) s = fmaf(hid[k], Wl2[k * 3 + t], s);
        out[g * 3 + t] = s;
    }
}

// ---------------- launch ----------------

extern "C" void kernel_launch(void* const* d_in, const int* in_sizes, int n_in,
                              void* d_out, int out_size, void* d_ws, size_t ws_size,
                              hipStream_t stream) {
    const float* x    = (const float*)d_in[0];
    const int*   ei   = (const int*)d_in[1];
    const float* ea   = (const float*)d_in[2];
    const int*   bat  = (const int*)d_in[3];
    const float* Wemb = (const float*)d_in[4];
    const float* bemb = (const float*)d_in[5];
    const float* W1   = (const float*)d_in[6];
    const float* b1   = (const float*)d_in[7];
    const float* W2   = (const float*)d_in[8];
    const float* W3   = (const float*)d_in[9];
    const float* b3   = (const float*)d_in[10];
    const float* Wl1  = (const float*)d_in[11];
    const float* bl1  = (const float*)d_in[12];
    const float* Wl2  = (const float*)d_in[13];
    const float* bl2  = (const float*)d_in[14];
    float* out = (float*)d_out;

    char* ws = (char*)d_ws;
    float*           c        = (float*)          (ws + 0);           // 25,600,000
    __hip_bfloat16*  a        = (__hip_bfloat16*) (ws + 25600000);    // 12,800,000
    __hip_bfloat16*  h16      = (__hip_bfloat16*) (ws + 38400000);    // 12,800,000
    int2*            perm_raw = (int2*)           (ws + 51200000);    // 12,800,000 (dense)
    int2*            perm2    = (int2*)           (ws + 64000000);    // 16,384,000 (CAP layout)
    int2*            rows     = (int2*)           (ws + 80384000);    //    800,000
    int2*            offcnt   = (int2*)           (ws + 81184000);    //  2,048,000
    float*           wdeg     = (float*)          (ws + 83232000);    //    400,000
    float*           gx       = (float*)          (ws + 83632000);    //    131,072
    __hip_bfloat16*  wpack    = (__hip_bfloat16*) (ws + 83763072);    //     73,728 -> ~83.8 MB

    local_sort_kernel<<<SC_BLOCKS, 256, 0, stream>>>(ei, ea, perm_raw, offcnt);
    bucket_csr_kernel<<<NB, 256, 0, stream>>>(perm_raw, offcnt, perm2, rows, wdeg);
    pack_w_kernel<<<NLAYER * 24, 64, 0, stream>>>(W1, W2, W3, wpack);

    embed_kernel<<<NNODES * 64 / 256, 256, 0, stream>>>(x, Wemb, bemb, h16);
    for (int l = 0; l < NLAYER; ++l) {
        gemm3_mfma_kernel<<<(NNODES + 63) / 64, 256, 0, stream>>>(
            h16, wdeg, wpack + (size_t)l * 24 * 512, b1 + l * 64, b3 + l * 64, a, c);
        edge_agg_kernel<<<(NNODES + 3) / 4, 256, 0, stream>>>(a, c, h16, rows, perm2);
    }
    pool_kernel<<<NGRAPH, 256, 0, stream>>>(h16, bat, gx);
    mlp_kernel<<<NGRAPH, 64, 0, stream>>>(gx, Wl1, bl1, Wl2, bl2, out);
}